// Round 1
// baseline (802.100 us; speedup 1.0000x reference)
//
#include <hip/hip_runtime.h>

#define NDET 600
#define IMG_HW (384 * 384)          // 147456 floats per mask row
#define NF4 (IMG_HW / 4)            // 36864 float4 per mask row
#define NMS_BLK 640
#define SCORE_THRESH 0.001f

// ---------------------------------------------------------------------------
// Kernel 1: class-shift + stable sort by score + sequential gaussian soft-NMS
// One block, 640 threads (thread tid owns sorted-position tid).
// ---------------------------------------------------------------------------
__global__ __launch_bounds__(NMS_BLK) void nms_kernel(
    const float* __restrict__ boxes, const float* __restrict__ scores,
    const int* __restrict__ labels, float* __restrict__ out_keep,
    float* __restrict__ out_score, int* __restrict__ keep_ws)
{
    const int tid = threadIdx.x;

    __shared__ float s_sc[NDET];                       // original-order scores
    __shared__ float sx1[NDET], sy1[NDET], sx2[NDET], sy2[NDET]; // shifted, orig order
    __shared__ float bx1[NDET], by1[NDET], bx2[NDET], by2[NDET]; // shifted, sorted
    __shared__ float bar[NDET], bsc[NDET];             // sorted area, score
    __shared__ int   borig[NDET];                      // sorted -> original idx
    __shared__ int   sact[NDET];                       // active flags (sorted order)
    __shared__ float sred[NMS_BLK];

    if (tid < NDET) s_sc[tid] = scores[tid];

    // ---- max over all box coords (2400 elems) ----
    float m = -1e30f;
    for (int k = tid; k < NDET * 4; k += NMS_BLK) m = fmaxf(m, boxes[k]);
    sred[tid] = m;
    __syncthreads();
    for (int off = NMS_BLK / 2; off > 0; off >>= 1) {
        if (tid < off) sred[tid] = fmaxf(sred[tid], sred[tid + off]);
        __syncthreads();
    }
    const float max_coord = sred[0] + 1.0f;

    // ---- class-aware shift (same fp ops as reference: coord + label*max_coord)
    if (tid < NDET) {
        const float shf = (float)labels[tid] * max_coord;
        sx1[tid] = boxes[4 * tid + 0] + shf;
        sy1[tid] = boxes[4 * tid + 1] + shf;
        sx2[tid] = boxes[4 * tid + 2] + shf;
        sy2[tid] = boxes[4 * tid + 3] + shf;
        sact[tid] = 1;
    }
    __syncthreads();

    // ---- stable descending rank (ties -> lower original index first) ----
    if (tid < NDET) {
        const float s_i = s_sc[tid];
        int r = 0;
        for (int j = 0; j < NDET; j++) {
            const float s_j = s_sc[j];
            r += (s_j > s_i) || (s_j == s_i && j < tid);
        }
        bx1[r] = sx1[tid]; by1[r] = sy1[tid];
        bx2[r] = sx2[tid]; by2[r] = sy2[tid];
        bar[r] = (sx2[tid] - sx1[tid]) * (sy2[tid] - sy1[tid]); // area from shifted coords (as ref)
        bsc[r] = s_i;
        borig[r] = tid;
    }
    __syncthreads();

    // ---- per-thread state in sorted order ----
    float myx1 = 0.f, myy1 = 0.f, myx2 = 0.f, myy2 = 0.f, mya = 0.f, mys = 0.f;
    int myact = 0, myorig = 0;
    if (tid < NDET) {
        myx1 = bx1[tid]; myy1 = by1[tid]; myx2 = bx2[tid]; myy2 = by2[tid];
        mya = bar[tid];  mys = bsc[tid];  myorig = borig[tid];
        myact = 1;
    }
    __syncthreads();

    // ---- sequential scan: kept detection i decays all later active j ----
    for (int i = 0; i < NDET; i++) {
        const int act_i = sact[i];       // broadcast LDS read (block-uniform)
        if (act_i) {
            const float ix1 = bx1[i], iy1 = by1[i], ix2 = bx2[i], iy2 = by2[i];
            const float ia = bar[i];
            if (tid > i && tid < NDET && myact) {
                const float w = fminf(myx2, ix2) - fmaxf(myx1, ix1);
                const float h = fminf(myy2, iy2) - fmaxf(myy1, iy1);
                if (w > 0.f && h > 0.f) {              // inter==0 => decay==1 exactly, skip
                    const float inter = w * h;
                    const float iou = inter / (mya + ia - inter);
                    mys *= expf(-(iou * iou) / 0.5f);  // SIGMA = 0.5
                    if (!(mys > SCORE_THRESH)) { myact = 0; sact[tid] = 0; }
                }
            }
        }
        __syncthreads();
    }

    // keep[j] == active state at j's own turn; active can only change at i < j,
    // so final myact == keep. Scatter back to original order.
    if (tid < NDET) {
        out_keep[myorig]  = myact ? 1.0f : 0.0f;
        out_score[myorig] = myact ? mys : 0.0f;
        keep_ws[myorig]   = myact;
    }
}

// ---------------------------------------------------------------------------
// Kernel 2: per-row match list (same class, unshifted IoU > 0.5), cnt, use_avg
// ---------------------------------------------------------------------------
__global__ __launch_bounds__(256) void match_kernel(
    const float* __restrict__ boxes, const int* __restrict__ labels,
    const int* __restrict__ keep_ws, int* __restrict__ cnt_ws,
    int* __restrict__ ua_ws, int* __restrict__ list_ws)
{
    const int i = blockIdx.x;
    const int tid = threadIdx.x;
    __shared__ int mflag[NDET];

    const float ix1 = boxes[4 * i + 0], iy1 = boxes[4 * i + 1];
    const float ix2 = boxes[4 * i + 2], iy2 = boxes[4 * i + 3];
    const float ia = (ix2 - ix1) * (iy2 - iy1);
    const int li = labels[i];

    for (int j = tid; j < NDET; j += 256) {
        const float jx1 = boxes[4 * j + 0], jy1 = boxes[4 * j + 1];
        const float jx2 = boxes[4 * j + 2], jy2 = boxes[4 * j + 3];
        const float ja = (jx2 - jx1) * (jy2 - jy1);
        float w = fminf(ix2, jx2) - fmaxf(ix1, jx1);
        float h = fminf(iy2, jy2) - fmaxf(iy1, jy1);
        w = fmaxf(w, 0.f); h = fmaxf(h, 0.f);
        const float inter = w * h;
        const float iou = inter / (ia + ja - inter);
        mflag[j] = (labels[j] == li) && (iou > 0.5f);
    }
    __syncthreads();

    if (tid == 0) {
        int c = 0;
        for (int j = 0; j < NDET; j++)
            if (mflag[j]) list_ws[i * NDET + (c++)] = j;
        cnt_ws[i] = c;
        ua_ws[i] = (keep_ws[i] && c > 1) ? 1 : 0;
    }
}

// ---------------------------------------------------------------------------
// Kernel 3: mask output. Copy row unless use_avg; else gather+avg matched rows.
// grid = (NF4/256, NDET), block = 256, one float4 per thread.
// ---------------------------------------------------------------------------
__global__ __launch_bounds__(256) void mask_kernel(
    const float4* __restrict__ masks, const int* __restrict__ cnt_ws,
    const int* __restrict__ ua_ws, const int* __restrict__ list_ws,
    float4* __restrict__ out)
{
    const int row = blockIdx.y;
    const int c4 = blockIdx.x * 256 + threadIdx.x;   // < NF4 by construction

    float4 r;
    if (!ua_ws[row]) {
        r = masks[(size_t)row * NF4 + c4];
    } else {
        const int c = cnt_ws[row];
        float4 acc = make_float4(0.f, 0.f, 0.f, 0.f);
        for (int k = 0; k < c; k++) {
            const int j = list_ws[row * NDET + k];
            const float4 v = masks[(size_t)j * NF4 + c4];
            acc.x += v.x; acc.y += v.y; acc.z += v.z; acc.w += v.w;
        }
        const float fc = (float)c;
        r.x = acc.x / fc; r.y = acc.y / fc; r.z = acc.z / fc; r.w = acc.w / fc;
    }
    out[(size_t)row * NF4 + c4] = r;
}

// ---------------------------------------------------------------------------
extern "C" void kernel_launch(void* const* d_in, const int* in_sizes, int n_in,
                              void* d_out, int out_size, void* d_ws, size_t ws_size,
                              hipStream_t stream) {
    const float* boxes  = (const float*)d_in[0];   // [600,4]
    const float* scores = (const float*)d_in[1];   // [600]
    const float* masks  = (const float*)d_in[2];   // [600,1,384,384]
    const int*   labels = (const int*)d_in[3];     // [600]

    float* out = (float*)d_out;                    // [keep(600) | scores(600) | masks(600*147456)]

    int* keep_ws = (int*)d_ws;                     // [600]
    int* cnt_ws  = keep_ws + NDET;                 // [600]
    int* ua_ws   = cnt_ws + NDET;                  // [600]
    int* list_ws = ua_ws + NDET;                   // [600*600]

    nms_kernel<<<1, NMS_BLK, 0, stream>>>(boxes, scores, labels,
                                          out, out + NDET, keep_ws);
    match_kernel<<<NDET, 256, 0, stream>>>(boxes, labels, keep_ws,
                                           cnt_ws, ua_ws, list_ws);
    mask_kernel<<<dim3(NF4 / 256, NDET), 256, 0, stream>>>(
        (const float4*)masks, cnt_ws, ua_ws, list_ws,
        (float4*)(out + 2 * NDET));
}